// Round 13
// baseline (60.420 us; speedup 1.0000x reference)
//
#include <hip/hip_runtime.h>
#include <cstdint>
#include <cstddef>

#define IN_K   6480   // 45*16*9
#define NOUT   6912   // 48*16*9
#define NB     64     // batch (C=1)
#define KPAD   6528   // 204 K-tiles of 32 (covers 6480; W K-dim is 6912 so rows exist; x pad = 0)
#define NKT    204
#define KSPLIT 12
#define KT_PER 17     // 204/12
#define NBUCKET 4096

typedef __attribute__((ext_vector_type(8))) short bf16x8;
typedef __attribute__((ext_vector_type(4))) float f32x4;
typedef __attribute__((ext_vector_type(4))) float float4v;

// Native bf16 convert (RTNE): compiler lowers pairs to v_cvt_pk_bf16_f32 on gfx950.
__device__ __forceinline__ short f2bf(float f) {
    return (short)__builtin_bit_cast(unsigned short, (__bf16)f);
}

// ---------------- K1: x -> bf16 A-fragments (fragment-ordered) ----------------
__global__ __launch_bounds__(256) void k_pre(const float* __restrict__ x,
                                             unsigned short* __restrict__ xfrag) {
    const int kt   = blockIdx.x;
    const int m    = threadIdx.x >> 6;
    const int lane = threadIdx.x & 63;
    const int b    = m * 16 + (lane & 15);
    const int k0   = kt * 32 + (lane >> 4) * 8;
    bf16x8 v;
#pragma unroll
    for (int j = 0; j < 8; ++j) {
        const int k = k0 + j;
        const float f = (k < IN_K) ? x[(size_t)b * IN_K + k] : 0.0f;
        v[j] = f2bf(f);
    }
    *(bf16x8*)(xfrag + ((size_t)(kt * 4 + m) * 64 + lane) * 8) = v;
}

// ---------------- K2: MFMA GEMM, direct-from-global W, depth-3 register pipeline ------------
// K-loop byte-identical to the proven round-6 kernel (57.9us, passed twice).
// grid (108, 12), block 256 (4 waves). Wave: 16 cols, all 64 batch rows, 17 K-tiles.
// Each set = 8 W-dword loads + 4 A-dwordx4 loads, prefetched 2 tiles ahead; the consumed
// set is always the OLDEST outstanding VMEM, so the compiler's wait lands at vmcnt(24)
// and keeps 2 sets in flight (round-5 lesson).
// EPILOGUE CHANGE (this round's single variable): non-atomic stores of per-K-split
// partials into part[ks][b][o] — each element written by exactly one block (column
// stripes disjoint), full 64B lines, NO RMW.  Tests the hypothesis that the 58us
// plateau = serialized atomic line-RMWs at the coherence point (1.9M line-RMWs).
__global__ __launch_bounds__(256) void k_gemm(const unsigned short* __restrict__ xfrag,
                                              const float* __restrict__ W,
                                              float* __restrict__ part) {
    const int lane  = threadIdx.x & 63;
    const int wv    = threadIdx.x >> 6;
    const int obase = blockIdx.x * 64 + wv * 16;
    const int ks    = blockIdx.y;
    const int kt0   = ks * KT_PER;
    const int g     = lane >> 4;          // 0..3 k-slice group
    const int r     = lane & 15;          // column within 16

    f32x4 acc[4];
#pragma unroll
    for (int m = 0; m < 4; ++m) acc[m] = f32x4{0.f, 0.f, 0.f, 0.f};

    const float*  __restrict__ wp = W + (size_t)(kt0 * 32 + g * 8) * NOUT + obase + r;
    const bf16x8* __restrict__ xf = (const bf16x8*)xfrag + (size_t)kt0 * 4 * 64 + lane;

    float  wA[8], wB[8], wC[8];
    bf16x8 aA[4], aB[4], aC[4];

#define LT(WF, AF, T)                                                     \
    {                                                                     \
        _Pragma("unroll")                                                 \
        for (int j = 0; j < 8; ++j)                                       \
            WF[j] = wp[((size_t)(T) * 32 + j) * NOUT];                    \
        _Pragma("unroll")                                                 \
        for (int m = 0; m < 4; ++m)                                       \
            AF[m] = xf[(size_t)((T) * 4 + m) * 64];                       \
    }

#define CT(WF, AF)                                                        \
    {                                                                     \
        bf16x8 bv;                                                        \
        _Pragma("unroll")                                                 \
        for (int j = 0; j < 8; ++j) bv[j] = f2bf(WF[j]);                  \
        acc[0] = __builtin_amdgcn_mfma_f32_16x16x32_bf16(AF[0], bv, acc[0], 0, 0, 0); \
        acc[1] = __builtin_amdgcn_mfma_f32_16x16x32_bf16(AF[1], bv, acc[1], 0, 0, 0); \
        acc[2] = __builtin_amdgcn_mfma_f32_16x16x32_bf16(AF[2], bv, acc[2], 0, 0, 0); \
        acc[3] = __builtin_amdgcn_mfma_f32_16x16x32_bf16(AF[3], bv, acc[3], 0, 0, 0); \
    }

    LT(wA, aA, 0)
    LT(wB, aB, 1)
#pragma unroll 1
    for (int i = 0; i < 5; ++i) {        // t = 0,3,6,9,12 -> computes tiles 0..14, loads to 16
        const int t = i * 3;
        LT(wC, aC, t + 2)  CT(wA, aA)
        LT(wA, aA, t + 3)  CT(wB, aB)
        LT(wB, aB, t + 4)  CT(wC, aC)
    }
    CT(wA, aA)                            // tile 15
    CT(wB, aB)                            // tile 16

    // C/D layout (m89-verified): col = lane&15, row = (lane>>4)*4 + reg.
    // Plain stores: lanes 0..15 hit 16 consecutive dwords -> full 64B lines.
    float* pb = part + (size_t)ks * NB * NOUT;
#pragma unroll
    for (int m = 0; m < 4; ++m) {
        float* sp = pb + (size_t)(m * 16 + g * 4) * NOUT + obase + r;
#pragma unroll
        for (int q = 0; q < 4; ++q)
            sp[(size_t)q * NOUT] = acc[m][q];
    }
#undef LT
#undef CT
}

// ---------------- K3: reduce partials + per-row approximate ranks via bucket sort ----------
__device__ __forceinline__ int bucket_of(float s) {
    float q = (s + 16.0f) * 128.0f;      // buckets of width 1/128 over [-16,16)
    int b = (int)q;
    return b < 0 ? 0 : (b > NBUCKET - 1 ? NBUCKET - 1 : b);
}

// 64 blocks (one per batch row), 1024 threads, float4 I/O, shfl-based scan (1 barrier).
// Pass 1 now sums the KSPLIT partials + bias (coalesced reads), stages row in LDS.
__global__ __launch_bounds__(1024) void k_rank(const float* __restrict__ part,
                                               const float* __restrict__ bias,
                                               const float* __restrict__ x0,
                                               float* __restrict__ out0,
                                               float* __restrict__ out1) {
    __shared__ unsigned int hist[NBUCKET];            // 16 KB
    __shared__ unsigned int base[NBUCKET];            // 16 KB
    __shared__ __align__(16) float srow[NOUT];        // 27 KB  (total 59.1 KB)
    __shared__ unsigned int wtot[16];

    const int row  = blockIdx.x;
    const int tid  = threadIdx.x;
    const int lane = tid & 63;
    const int wid  = tid >> 6;
    const float4v* __restrict__ b4 = (const float4v*)bias;

    for (int i = tid; i < NBUCKET; i += 1024) hist[i] = 0u;
    __syncthreads();

    // pass 1: sum partials + bias -> LDS, histogram (6912/4 = 1728 float4s)
    for (int i = tid; i < NOUT / 4; i += 1024) {
        float4v v = b4[i];
#pragma unroll 1
        for (int ks = 0; ks < KSPLIT; ++ks)
            v += *(const float4v*)(part + ((size_t)ks * NB + row) * NOUT + i * 4);
        *(float4v*)&srow[i * 4] = v;
#pragma unroll
        for (int j = 0; j < 4; ++j) atomicAdd(&hist[bucket_of(v[j])], 1u);
    }
    __syncthreads();

    // exclusive scan: each thread owns 4 buckets; wave-shfl scan + wave-total prefix
    unsigned int c[4];
    unsigned int run = 0u;
#pragma unroll
    for (int j = 0; j < 4; ++j) { c[j] = run; run += hist[tid * 4 + j]; }

    unsigned int inc = run;
#pragma unroll
    for (int d = 1; d < 64; d <<= 1) {
        const unsigned int v = __shfl_up(inc, d, 64);
        if (lane >= d) inc += v;
    }
    if (lane == 63) wtot[wid] = inc;
    __syncthreads();

    unsigned int wbase = 0u;
#pragma unroll
    for (int i = 0; i < 16; ++i) wbase += (i < wid) ? wtot[i] : 0u;
    const unsigned int tbase = wbase + inc - run;

#pragma unroll
    for (int j = 0; j < 4; ++j) {
        base[tid * 4 + j] = tbase + c[j];
        hist[tid * 4 + j] = 0u;                  // reuse as intra-bucket counter
    }
    __syncthreads();

    // pass 2: ranks + outputs (score from LDS)
    float* o1 = out1 + (size_t)row * NOUT;
    float* o0 = out0 + (size_t)row * NOUT;
    for (int i = tid; i < NOUT / 4; i += 1024) {
        const float4v v = *(const float4v*)&srow[i * 4];
        const int i4 = i * 4;
        float4v xv;
        if (i4 < IN_K) xv = *(const float4v*)(x0 + i4);    // IN_K % 4 == 0
        else           xv = float4v{0.f, 0.f, 0.f, 0.f};
        float4v rv;
#pragma unroll
        for (int j = 0; j < 4; ++j) {
            const int bkt = bucket_of(v[j]);
            const unsigned int rk = base[bkt] + atomicAdd(&hist[bkt], 1u);
            rv[j] = (float)rk;
            o0[rk] = xv[j];
        }
        *(float4v*)(o1 + i4) = rv;
    }
}

extern "C" void kernel_launch(void* const* d_in, const int* in_sizes, int n_in,
                              void* d_out, int out_size, void* d_ws, size_t ws_size,
                              hipStream_t stream) {
    const float* x    = (const float*)d_in[0];   // 64 x 6480
    const float* W    = (const float*)d_in[1];   // 6912 x 6912
    const float* bias = (const float*)d_in[2];   // 6912

    float* out0 = (float*)d_out;
    float* out1 = out0 + (size_t)NB * NOUT;

    unsigned short* xfrag = (unsigned short*)d_ws;                     // 835,584 B
    float* part = (float*)((char*)d_ws + (size_t)KPAD * NB * 2);       // 12 x 64 x 6912 fp32 = 21.2 MB

    k_pre<<<NKT, 256, 0, stream>>>(x, xfrag);
    k_gemm<<<dim3(108, KSPLIT), 256, 0, stream>>>(xfrag, W, part);
    k_rank<<<NB, 1024, 0, stream>>>(part, bias, x, out0, out1);
}